// Round 8
// baseline (1240.297 us; speedup 1.0000x reference)
//
#include <hip/hip_runtime.h>

#define NN 20000      // nodes
#define NE 320000     // edges
#define NB 8          // batch
#define NT 12         // time steps
// H = 64, OUT = 120 (5 hops x 24), G layout node-major: G[(n*NB+b)*24 + j]

typedef unsigned int u32;
typedef short bf16x8 __attribute__((ext_vector_type(8)));
typedef float f32x4 __attribute__((ext_vector_type(4)));

union U8 { u32 u[4]; bf16x8 v; };

__device__ __forceinline__ float bcast(float v, int k) {
  return __int_as_float(__builtin_amdgcn_readlane(__float_as_int(v), k));
}
// dst = { lo16 = bf16(a), hi16 = bf16(b) }  (RNE, hardware)
__device__ __forceinline__ u32 cvt_pk_bf16(float a, float b) {
  u32 r;
  asm("v_cvt_pk_bf16_f32 %0, %1, %2" : "=v"(r) : "v"(a), "v"(b));
  return r;
}
__device__ __forceinline__ float rcpf(float x) {
  float r;
  asm("v_rcp_f32 %0, %1" : "=v"(r) : "v"(x));
  return r;
}
__device__ __forceinline__ unsigned short f2bf(float f) {
  u32 u = __float_as_uint(f);
  u32 r = (u + 0x7FFFu + ((u >> 16) & 1u)) >> 16;
  return (unsigned short)r;
}
__device__ __forceinline__ float bf2f(unsigned short s) {
  return __uint_as_float(((u32)s) << 16);
}

// ---------------------------------------------------------------- degree
__global__ void deg_kernel(const int* __restrict__ ei, const float* __restrict__ ew,
                           float* __restrict__ wsum_f, float* __restrict__ wsum_b,
                           int* __restrict__ cnt_f, int* __restrict__ cnt_b) {
  int e = blockIdx.x * 256 + threadIdx.x;
  if (e >= NE) return;
  int s = ei[e], t = ei[NE + e];
  float wv = ew[e];
  atomicAdd(&wsum_f[t], wv);
  atomicAdd(&cnt_f[t], 1);
  atomicAdd(&wsum_b[s], wv);
  atomicAdd(&cnt_b[s], 1);
}

// ---------------------------------------------------------------- scan (1 block, int4)
__global__ __launch_bounds__(1024) void scan_kernel(
    const int* __restrict__ cnt_f, const int* __restrict__ cnt_b,
    int* __restrict__ rp_f, int* __restrict__ rp_b,
    int* __restrict__ cur_f, int* __restrict__ cur_b) {
  __shared__ int sm[1024];
  const int tid = threadIdx.x;
  for (int pass = 0; pass < 2; ++pass) {
    const int* cnt = pass ? cnt_b : cnt_f;
    int* rp  = pass ? rp_b  : rp_f;
    int* cur = pass ? cur_b : cur_f;
    const int base = tid * 20;
    int4 c4[5];
    int s = 0;
    if (base < NN) {
      const int4* cp = (const int4*)(cnt + base);
#pragma unroll
      for (int j = 0; j < 5; j++) c4[j] = cp[j];
#pragma unroll
      for (int j = 0; j < 5; j++) s += c4[j].x + c4[j].y + c4[j].z + c4[j].w;
    }
    __syncthreads();
    sm[tid] = s;
    __syncthreads();
    for (int off = 1; off < 1024; off <<= 1) {
      int v = (tid >= off) ? sm[tid - off] : 0;
      __syncthreads();
      sm[tid] += v;
      __syncthreads();
    }
    if (base < NN) {
      int run = sm[tid] - s;
      int4* rp4  = (int4*)(rp + base);
      int4* cur4 = (int4*)(cur + base);
#pragma unroll
      for (int j = 0; j < 5; j++) {
        int4 o;
        o.x = run; run += c4[j].x;
        o.y = run; run += c4[j].y;
        o.z = run; run += c4[j].z;
        o.w = run; run += c4[j].w;
        rp4[j] = o;
        cur4[j] = o;
      }
    }
    if (tid == 1023) rp[NN] = sm[1023];
  }
}

// ---------------------------------------------------------------- CSR fill
__global__ void fill_kernel(const int* __restrict__ ei, const float* __restrict__ ew,
                            const float* __restrict__ wsum_f, const float* __restrict__ wsum_b,
                            int* __restrict__ cur_f, int* __restrict__ cur_b,
                            int* __restrict__ col_f, float* __restrict__ wn_f,
                            int* __restrict__ col_b, float* __restrict__ wn_b) {
  int e = blockIdx.x * 256 + threadIdx.x;
  if (e >= NE) return;
  int s = ei[e], t = ei[NE + e];
  float wv = ew[e];
  int slot = atomicAdd(&cur_f[t], 1);
  float w1 = wsum_f[t];
  col_f[slot] = s;
  wn_f[slot] = (w1 > 0.f) ? wv / w1 : 0.f;
  slot = atomicAdd(&cur_b[s], 1);
  float w2 = wsum_b[s];
  col_b[slot] = t;
  wn_b[slot] = (w2 > 0.f) ? wv / w2 : 0.f;
}

// ---------------------------------------------------------------- nbq + W2 + (wcat in tail blocks)
#define NBLK_NB 313   // ceil(NN/64)
__global__ __launch_bounds__(512) void nb_kernel(
    const float* __restrict__ node_emb, const float* __restrict__ enc_b,
    const float* __restrict__ w_ih, const float* __restrict__ b_ih,
    const float* __restrict__ enc_w, const float* __restrict__ b_hh,
    const float* __restrict__ filt_w, const float* __restrict__ filt_b,
    const float* __restrict__ dec_w, const float* __restrict__ dec_b,
    float* __restrict__ nbq, float* __restrict__ W2,
    float* __restrict__ Wcat, float* __restrict__ cbv) {
  const int tid = threadIdx.x;
  if (blockIdx.x >= NBLK_NB) {
    // ---- wcat part: Wcat[64][128] = filt_w_i @ dec_w (padded), cbv
    int idx = (blockIdx.x - NBLK_NB) * 512 + tid;
    if (idx < 64 * 128) {
      int k = idx >> 7, j = idx & 127;
      float acc = 0.f;
      if (j < 120) {
        int wi = j / 24, jj = j - wi * 24;
        for (int c = 0; c < 64; c++)
          acc += filt_w[(wi * 64 + k) * 64 + c] * dec_w[c * 24 + jj];
      }
      Wcat[idx] = acc;
    } else if (idx < 64 * 128 + 24) {
      int jj = idx - 64 * 128;
      float acc = dec_b[jj];
      for (int c = 0; c < 64; c++) acc += filt_b[c] * dec_w[c * 24 + jj];
      cbv[jj] = acc;
    }
    return;
  }
  __shared__ float w3[64 * 64 * 4];
  for (int idx = tid; idx < 192 * 64; idx += 512) {
    int row = idx >> 6, k = idx & 63;
    w3[((k << 6) + (row & 63)) * 4 + (row >> 6)] = w_ih[idx];
  }
  __syncthreads();
  const int lane = tid & 63, wave = tid >> 6;
  const float4* w3v = (const float4*)w3;
  const float eb = enc_b[lane];
  const float bir = b_ih[lane], biz = b_ih[64 + lane], bin_ = b_ih[128 + lane];
  const float bhr = b_hh[lane], bhz = b_hh[64 + lane];
#pragma unroll 1
  for (int pass = 0; pass < 8; ++pass) {
    const int n = blockIdx.x * 64 + pass * 8 + wave;
    if (n >= NN) break;
    float ne = node_emb[n * 64 + lane] + eb;
    float ar = bir, az = biz, an = bin_;
#pragma unroll 16
    for (int k = 0; k < 64; k++) {
      float4 w = w3v[(k << 6) + lane];
      float nk = bcast(ne, k);
      ar = fmaf(w.x, nk, ar);
      az = fmaf(w.y, nk, az);
      an = fmaf(w.z, nk, an);
    }
    // layout: q = gt*16 + (f>>2), element f&3; fold b_hh into r,z
    nbq[(((lane >> 2)) * NN + n) * 4 + (lane & 3)]      = ar + bhr;
    nbq[((16 + (lane >> 2)) * NN + n) * 4 + (lane & 3)] = az + bhz;
    nbq[((32 + (lane >> 2)) * NN + n) * 4 + (lane & 3)] = an;
  }
  if (blockIdx.x == 0 && tid < 384) {
    int f = tid / 192, g = tid - f * 192;
    float acc = 0.f;
    for (int k2 = 0; k2 < 64; k2++) acc += enc_w[f * 64 + k2] * w_ih[g * 64 + k2];
    W2[f * 192 + g] = acc;
  }
}

// ---------------------------------------------------------------- MFMA GRU + MFMA epilogue
// 4 waves / 256 threads, static LDS 48KB (3 blocks/CU):
//   [0,6144) whh-hi frags; [6144,12288) whh-lo frags
//   Block covers 8 nodes x 8 batches (dense G writes):
//     node = blockIdx*8 + (sl&7), bb = wave*2 + (sl>>3)
//   h-exchange in-register via ds_bpermute (see R7 comment).
//   x software-pipeline: unroll-3, prefetch distance 3 (named regs, static idx).
//   epilogue overlays [0,4096) wcat-hi, [4096,8192) wcat-lo.
#define MFMA(acc, a, b) acc = __builtin_amdgcn_mfma_f32_16x16x32_bf16((a), (b), acc, 0, 0, 0)
#define BP(addr, reg) __builtin_amdgcn_ds_bpermute((addr), (int)(reg))

__global__ __launch_bounds__(256, 3) void gru_kernel(
    const float* __restrict__ x, const float* __restrict__ nbq,
    const float* __restrict__ W2, const float* __restrict__ b_hh,
    const float* __restrict__ w_hh, const float* __restrict__ Wcat,
    const float* __restrict__ cbv,
    float* __restrict__ G0, float* __restrict__ G1f, float* __restrict__ G2f,
    float* __restrict__ G1b, float* __restrict__ G2b) {
  __shared__ u32 lds[12288];
  const int tid = threadIdx.x;

  // ---- whh hi/lo A-frag tables, idx-major (conflict-free stores)
  for (int idx = tid; idx < 6144; idx += 256) {
    int tile = idx >> 9, ks = (idx >> 8) & 1, ln = (idx >> 2) & 63, r = idx & 3;
    int gate = tile * 16 + (ln & 15);
    int k2 = ks * 32 + ((ln >> 4) & 3) * 8 + r * 2;
    float w0 = w_hh[gate * 64 + k2];
    float w1 = w_hh[gate * 64 + k2 + 1];
    unsigned short h0 = f2bf(w0), h1 = f2bf(w1);
    unsigned short l0 = f2bf(w0 - bf2f(h0)), l1 = f2bf(w1 - bf2f(h1));
    lds[idx]        = (u32)h0 | ((u32)h1 << 16);
    lds[6144 + idx] = (u32)l0 | ((u32)l1 << 16);
  }
  __syncthreads();

  const int lane = tid & 63, wave = tid >> 6;
  const int g = lane >> 4, sl = lane & 15;
  const int node = blockIdx.x * 8 + (sl & 7);
  const int bb = wave * 2 + (sl >> 3);
  // bpermute source-lane byte addresses (lane-constant)
  const int addrA = (((g & 1) * 32) + sl) * 4;
  const int addrB = addrA + 64;
  const bool fbHi = (g >= 2);

#define LDW(tile, ks, part) (*(const bf16x8*)(lds + (part) * 6144 + (((tile) * 2 + (ks)) << 8) + (lane << 2)))

// build one (hb, lb) B-frag pair for k-half fo/2 (fo = 0 or 2)
#define BLD(hb, lb, fo) { \
    int a_, b_; \
    a_ = BP(addrA, hiP[fo]); b_ = BP(addrA, hiP[(fo) + 1]); hb.u[0] = fbHi ? b_ : a_; \
    a_ = BP(addrA, hiQ[fo]); b_ = BP(addrA, hiQ[(fo) + 1]); hb.u[1] = fbHi ? b_ : a_; \
    a_ = BP(addrB, hiP[fo]); b_ = BP(addrB, hiP[(fo) + 1]); hb.u[2] = fbHi ? b_ : a_; \
    a_ = BP(addrB, hiQ[fo]); b_ = BP(addrB, hiQ[(fo) + 1]); hb.u[3] = fbHi ? b_ : a_; \
    a_ = BP(addrA, loP[fo]); b_ = BP(addrA, loP[(fo) + 1]); lb.u[0] = fbHi ? b_ : a_; \
    a_ = BP(addrA, loQ[fo]); b_ = BP(addrA, loQ[(fo) + 1]); lb.u[1] = fbHi ? b_ : a_; \
    a_ = BP(addrB, loP[fo]); b_ = BP(addrB, loP[(fo) + 1]); lb.u[2] = fbHi ? b_ : a_; \
    a_ = BP(addrB, loQ[fo]); b_ = BP(addrB, loQ[(fo) + 1]); lb.u[3] = fbHi ? b_ : a_; \
  }

  // W2 (x-side) per-lane regs: lanes<16 carry k=0,1; others zero
  u32 w2h[12], w2l[12];
#pragma unroll
  for (int tl = 0; tl < 12; tl++) {
    float w0 = W2[tl * 16 + sl], w1 = W2[192 + tl * 16 + sl];
    u32 ph = cvt_pk_bf16(w0, w1);
    float lo0 = w0 - __uint_as_float(ph << 16);
    float lo1 = w1 - __uint_as_float(ph & 0xffff0000u);
    u32 pl = cvt_pk_bf16(lo0, lo1);
    w2h[tl] = (lane < 16) ? ph : 0u;
    w2l[tl] = (lane < 16) ? pl : 0u;
  }

  // acc inits: nbA=r(+bhh), nbB=z(+bhh), nbC=n(x-side), bhnv=b_hh n-part
  f32x4 nbA[4], nbB[4], nbC[4], bhnv[4];
#pragma unroll
  for (int fb = 0; fb < 4; fb++) {
    nbA[fb]  = *(const f32x4*)(nbq + ((size_t)(fb * 4 + g) * NN + node) * 4);
    nbB[fb]  = *(const f32x4*)(nbq + ((size_t)(16 + fb * 4 + g) * NN + node) * 4);
    nbC[fb]  = *(const f32x4*)(nbq + ((size_t)(32 + fb * 4 + g) * NN + node) * 4);
    bhnv[fb] = *(const f32x4*)(b_hh + 128 + fb * 16 + g * 4);
  }

  f32x4 hreg[4];
#pragma unroll
  for (int fb = 0; fb < 4; fb++) hreg[fb] = (f32x4){0.f, 0.f, 0.f, 0.f};

  // packed h exchange registers (hi/lo plane, r-pairs P=01 Q=23)
  u32 hiP[4], hiQ[4], loP[4], loQ[4];

  const float* xptr = x + ((size_t)(bb * NT) * NN + node) * 2;

  U8 hb0, hb1, lb0, lb1;

  // one GRU timestep; xv = this step's input, doH = include h-recurrence
  auto body = [&](float2 xv, bool doH) {
    // x B-frag: k01=xh, k23=xl, k45=xh (garbage in lanes g>0 is killed by A=0)
    u32 xhw = cvt_pk_bf16(xv.x, xv.y);
    float xl0 = xv.x - __uint_as_float(xhw << 16);
    float xl1 = xv.y - __uint_as_float(xhw & 0xffff0000u);
    u32 xlw = cvt_pk_bf16(xl0, xl1);
    U8 xB;
    xB.u[0] = xhw; xB.u[1] = xlw; xB.u[2] = xhw; xB.u[3] = 0u;

    if (doH) { BLD(hb0, lb0, 0); BLD(hb1, lb1, 2); }

#pragma unroll
    for (int fb = 0; fb < 4; fb++) {
      f32x4 aR = nbA[fb], aZ = nbB[fb], aXN = nbC[fb], aHN = bhnv[fb];
      if (doH) {
        bf16x8 Ah0 = LDW(fb, 0, 0), Al0 = LDW(fb, 0, 1);
        bf16x8 Ah1 = LDW(fb, 1, 0), Al1 = LDW(fb, 1, 1);
        MFMA(aR, Ah0, hb0.v); MFMA(aR, Ah0, lb0.v); MFMA(aR, Al0, hb0.v);
        MFMA(aR, Ah1, hb1.v); MFMA(aR, Ah1, lb1.v); MFMA(aR, Al1, hb1.v);
        bf16x8 Bh0 = LDW(4 + fb, 0, 0), Bl0 = LDW(4 + fb, 0, 1);
        bf16x8 Bh1 = LDW(4 + fb, 1, 0), Bl1 = LDW(4 + fb, 1, 1);
        MFMA(aZ, Bh0, hb0.v); MFMA(aZ, Bh0, lb0.v); MFMA(aZ, Bl0, hb0.v);
        MFMA(aZ, Bh1, hb1.v); MFMA(aZ, Bh1, lb1.v); MFMA(aZ, Bl1, hb1.v);
        bf16x8 Ch0 = LDW(8 + fb, 0, 0), Cl0 = LDW(8 + fb, 0, 1);
        bf16x8 Ch1 = LDW(8 + fb, 1, 0), Cl1 = LDW(8 + fb, 1, 1);
        MFMA(aHN, Ch0, hb0.v); MFMA(aHN, Ch0, lb0.v); MFMA(aHN, Cl0, hb0.v);
        MFMA(aHN, Ch1, hb1.v); MFMA(aHN, Ch1, lb1.v); MFMA(aHN, Cl1, hb1.v);
      }
      // x-side: one MFMA per gate (3-term split packed along K)
      U8 aW;
      aW.u[0] = w2h[fb];     aW.u[1] = w2h[fb];     aW.u[2] = w2l[fb];     aW.u[3] = 0u;
      MFMA(aR, aW.v, xB.v);
      aW.u[0] = w2h[4 + fb]; aW.u[1] = w2h[4 + fb]; aW.u[2] = w2l[4 + fb];
      MFMA(aZ, aW.v, xB.v);
      aW.u[0] = w2h[8 + fb]; aW.u[1] = w2h[8 + fb]; aW.u[2] = w2l[8 + fb];
      MFMA(aXN, aW.v, xB.v);

      // gate math (lane-local), pack h hi/lo planes into exchange regs
      float hv[4];
#pragma unroll
      for (int r = 0; r < 4; r++) {
        float rr = rcpf(1.f + __expf(-aR[r]));
        float zz = rcpf(1.f + __expf(-aZ[r]));
        float nv = fmaf(rr, aHN[r], aXN[r]);
        float th = fmaf(-2.f, rcpf(1.f + __expf(2.f * nv)), 1.f);
        float h2 = fmaf(zz, hreg[fb][r] - th, th);
        hreg[fb][r] = h2;
        hv[r] = h2;
      }
      u32 hA = cvt_pk_bf16(hv[0], hv[1]);
      u32 hB = cvt_pk_bf16(hv[2], hv[3]);
      float l0 = hv[0] - __uint_as_float(hA << 16);
      float l1 = hv[1] - __uint_as_float(hA & 0xffff0000u);
      float l2 = hv[2] - __uint_as_float(hB << 16);
      float l3 = hv[3] - __uint_as_float(hB & 0xffff0000u);
      hiP[fb] = hA;
      hiQ[fb] = hB;
      loP[fb] = cvt_pk_bf16(l0, l1);
      loQ[fb] = cvt_pk_bf16(l2, l3);
    }
  };

  // ---- software-pipelined t-loop: prefetch distance 3, static reg rotation
  float2 xc0 = *(const float2*)(xptr);
  float2 xc1 = *(const float2*)(xptr + (size_t)(NN * 2));
  float2 xc2 = *(const float2*)(xptr + (size_t)2 * (NN * 2));
#pragma unroll 1
  for (int tb = 0; tb < 4; tb++) {
    float2 xn0, xn1, xn2;
    if (tb < 3) {
      xn0 = *(const float2*)(xptr + (size_t)(3 * tb + 3) * (NN * 2));
      xn1 = *(const float2*)(xptr + (size_t)(3 * tb + 4) * (NN * 2));
      xn2 = *(const float2*)(xptr + (size_t)(3 * tb + 5) * (NN * 2));
    }
    body(xc0, tb != 0);
    body(xc1, true);
    body(xc2, true);
    xc0 = xn0; xc1 = xn1; xc2 = xn2;
  }

  // ---- epilogue: out120 = h @ Wcat (3-term split MFMA)
  __syncthreads();   // all waves done with whh frag region
  for (int idx = tid; idx < 4096; idx += 256) {
    int tile = idx >> 9, ks = (idx >> 8) & 1, ln = (idx >> 2) & 63, r = idx & 3;
    int j = tile * 16 + (ln & 15);
    int k2 = ks * 32 + ((ln >> 4) & 3) * 8 + r * 2;
    float w0 = Wcat[k2 * 128 + j];
    float w1 = Wcat[(k2 + 1) * 128 + j];
    unsigned short h0 = f2bf(w0), h1 = f2bf(w1);
    unsigned short l0 = f2bf(w0 - bf2f(h0)), l1 = f2bf(w1 - bf2f(h1));
    lds[idx]        = (u32)h0 | ((u32)h1 << 16);
    lds[4096 + idx] = (u32)l0 | ((u32)l1 << 16);
  }
  __syncthreads();
  BLD(hb0, lb0, 0); BLD(hb1, lb1, 2);

#define LDC(tile, ks, part) (*(const bf16x8*)(lds + (part) * 4096 + (((tile) * 2 + (ks)) << 8) + (lane << 2)))
#pragma unroll
  for (int tile = 0; tile < 8; tile++) {
    f32x4 acc = (f32x4){0.f, 0.f, 0.f, 0.f};
    bf16x8 Ah0 = LDC(tile, 0, 0), Al0 = LDC(tile, 0, 1);
    MFMA(acc, Ah0, hb0.v); MFMA(acc, Ah0, lb0.v); MFMA(acc, Al0, hb0.v);
    bf16x8 Ah1 = LDC(tile, 1, 0), Al1 = LDC(tile, 1, 1);
    MFMA(acc, Ah1, hb1.v); MFMA(acc, Ah1, lb1.v); MFMA(acc, Al1, hb1.v);
#pragma unroll
    for (int r = 0; r < 4; r++) {
      int j = tile * 16 + g * 4 + r;
      if (j < 120) {
        int wi = j / 24, jj = j - wi * 24;
        float val = acc[r];
        if (wi == 0) val += cbv[jj];
        float* gb = (wi == 0) ? G0 : (wi == 1) ? G1f : (wi == 2) ? G2f : (wi == 3) ? G1b : G2b;
        gb[((size_t)node * NB + bb) * 24 + jj] = val;   // node-major, dense per block
      }
    }
  }
}

// ---------------------------------------------------------------- hop1: G1f += Pf G2f | G1b += Pb G2b
// one wave per (n, dir); lanes 0-47 hold the 192-float row as float4
__global__ __launch_bounds__(256) void hop1_kernel(
    float* __restrict__ G1f, const float* __restrict__ G2f,
    float* __restrict__ G1b, const float* __restrict__ G2b,
    const int* __restrict__ rp_f, const int* __restrict__ col_f, const float* __restrict__ wn_f,
    const int* __restrict__ rp_b, const int* __restrict__ col_b, const float* __restrict__ wn_b) {
  const int wv = threadIdx.x >> 6;
  const int lane = threadIdx.x & 63;
  const int task = blockIdx.x * 4 + wv;
  const int fwd = task < NN;
  const int n = fwd ? task : task - NN;
  const int* rp  = fwd ? rp_f : rp_b;
  const int* col = fwd ? col_f : col_b;
  const float* wn = fwd ? wn_f : wn_b;
  const float4* src = (const float4*)(fwd ? G2f : G2b);
  float4* dst = (float4*)(fwd ? G1f : G1b);
  const int e0 = rp[n], e1 = rp[n + 1];
  if (lane >= 48) return;
  float4 acc = {0.f, 0.f, 0.f, 0.f};
  for (int e = e0; e < e1; ++e) {
    const int c = col[e];
    const float w = wn[e];
    float4 v = src[(size_t)c * 48 + lane];
    acc.x = fmaf(w, v.x, acc.x);
    acc.y = fmaf(w, v.y, acc.y);
    acc.z = fmaf(w, v.z, acc.z);
    acc.w = fmaf(w, v.w, acc.w);
  }
  float4 d = dst[(size_t)n * 48 + lane];
  d.x += acc.x; d.y += acc.y; d.z += acc.z; d.w += acc.w;
  dst[(size_t)n * 48 + lane] = d;
}

// ---------------------------------------------------------------- hop2: G0 += Pf G1f + Pb G1b
__global__ __launch_bounds__(256) void hop2_kernel(
    float* __restrict__ G0, const float* __restrict__ G1f, const float* __restrict__ G1b,
    const int* __restrict__ rp_f, const int* __restrict__ col_f, const float* __restrict__ wn_f,
    const int* __restrict__ rp_b, const int* __restrict__ col_b, const float* __restrict__ wn_b) {
  const int wv = threadIdx.x >> 6;
  const int lane = threadIdx.x & 63;
  const int n = blockIdx.x * 4 + wv;
  if (lane >= 48) return;
  const float4* s1 = (const float4*)G1f;
  const float4* s2 = (const float4*)G1b;
  float4* dst = (float4*)G0;
  float4 acc = dst[(size_t)n * 48 + lane];
  int e0 = rp_f[n], e1 = rp_f[n + 1];
  for (int e = e0; e < e1; ++e) {
    const int c = col_f[e];
    const float w = wn_f[e];
    float4 v = s1[(size_t)c * 48 + lane];
    acc.x = fmaf(w, v.x, acc.x);
    acc.y = fmaf(w, v.y, acc.y);
    acc.z = fmaf(w, v.z, acc.z);
    acc.w = fmaf(w, v.w, acc.w);
  }
  e0 = rp_b[n]; e1 = rp_b[n + 1];
  for (int e = e0; e < e1; ++e) {
    const int c = col_b[e];
    const float w = wn_b[e];
    float4 v = s2[(size_t)c * 48 + lane];
    acc.x = fmaf(w, v.x, acc.x);
    acc.y = fmaf(w, v.y, acc.y);
    acc.z = fmaf(w, v.z, acc.z);
    acc.w = fmaf(w, v.w, acc.w);
  }
  dst[(size_t)n * 48 + lane] = acc;
}

// ---------------------------------------------------------------- G0[n][b][24] -> out[b][t][n][f]
__global__ __launch_bounds__(256) void reorder_kernel(const float* __restrict__ G0,
                                                      float* __restrict__ out) {
  __shared__ float tile[32 * 193];
  const int n0 = blockIdx.x * 32;
  const int tid = threadIdx.x;
  for (int idx = tid; idx < 6144; idx += 256) {
    int i = idx / 192, r = idx - i * 192;
    tile[i * 193 + r] = G0[(size_t)n0 * 192 + idx];
  }
  __syncthreads();
  for (int idx = tid; idx < 6144; idx += 256) {
    int b = idx / 768;
    int rem = idx - b * 768;
    int t = rem >> 6;
    int rem2 = rem & 63;
    int i = rem2 >> 1, f = rem2 & 1;
    out[(((size_t)b * NT + t) * NN + n0 + i) * 2 + f] = tile[i * 193 + b * 24 + t * 2 + f];
  }
}

// ----------------------------------------------------------------
extern "C" void kernel_launch(void* const* d_in, const int* in_sizes, int n_in,
                              void* d_out, int out_size, void* d_ws, size_t ws_size,
                              hipStream_t stream) {
  const float* x        = (const float*)d_in[0];
  const int*   ei       = (const int*)d_in[1];
  const float* ew       = (const float*)d_in[2];
  const float* enc_w    = (const float*)d_in[3];
  const float* enc_b    = (const float*)d_in[4];
  const float* node_emb = (const float*)d_in[5];
  const float* w_ih     = (const float*)d_in[6];
  const float* w_hh     = (const float*)d_in[7];
  const float* b_ih     = (const float*)d_in[8];
  const float* b_hh     = (const float*)d_in[9];
  const float* filt_w   = (const float*)d_in[10];
  const float* filt_b   = (const float*)d_in[11];
  const float* dec_w    = (const float*)d_in[12];
  const float* dec_b    = (const float*)d_in[13];
  float* out = (float*)d_out;

  char* p = (char*)d_ws;
  auto alloc = [&](size_t bytes) {
    char* r = p;
    p += (bytes + 255) & ~(size_t)255;
    return r;
  };
  const size_t BN24 = (size_t)NB * NN * 24;
  float* G0   = (float*)alloc(BN24 * 4);
  float* G1f  = (float*)alloc(BN24 * 4);
  float* G2f  = (float*)alloc(BN24 * 4);
  float* G1b  = (float*)alloc(BN24 * 4);
  float* G2b  = (float*)alloc(BN24 * 4);
  float* nbq  = (float*)alloc((size_t)NN * 192 * 4);
  int* rp_f   = (int*)alloc((NN + 1) * 4);
  int* rp_b   = (int*)alloc((NN + 1) * 4);
  char* zreg  = alloc(4 * NN * 4);        // wsum_f, wsum_b, cnt_f, cnt_b (zeroed)
  float* wsum_f = (float*)zreg;
  float* wsum_b = wsum_f + NN;
  int*   cnt_f  = (int*)(wsum_b + NN);
  int*   cnt_b  = cnt_f + NN;
  int* cur_f  = (int*)alloc(NN * 4);
  int* cur_b  = (int*)alloc(NN * 4);
  int* col_f  = (int*)alloc((size_t)NE * 4);
  float* wn_f = (float*)alloc((size_t)NE * 4);
  int* col_b  = (int*)alloc((size_t)NE * 4);
  float* wn_b = (float*)alloc((size_t)NE * 4);
  float* Wcat = (float*)alloc(64 * 128 * 4);
  float* cbv  = (float*)alloc(32 * 4);
  float* W2   = (float*)alloc(384 * 4);

  hipMemsetAsync(zreg, 0, 4 * NN * 4, stream);
  deg_kernel<<<(NE + 255) / 256, 256, 0, stream>>>(ei, ew, wsum_f, wsum_b, cnt_f, cnt_b);
  scan_kernel<<<1, 1024, 0, stream>>>(cnt_f, cnt_b, rp_f, rp_b, cur_f, cur_b);
  fill_kernel<<<(NE + 255) / 256, 256, 0, stream>>>(ei, ew, wsum_f, wsum_b, cur_f, cur_b,
                                                    col_f, wn_f, col_b, wn_b);
  nb_kernel<<<NBLK_NB + 17, 512, 0, stream>>>(node_emb, enc_b, w_ih, b_ih, enc_w, b_hh,
                                              filt_w, filt_b, dec_w, dec_b,
                                              nbq, W2, Wcat, cbv);
  gru_kernel<<<NN / 8, 256, 0, stream>>>(x, nbq, W2, b_hh, w_hh, Wcat, cbv,
                                         G0, G1f, G2f, G1b, G2b);
  hop1_kernel<<<2 * NN / 4, 256, 0, stream>>>(G1f, G2f, G1b, G2b,
                                              rp_f, col_f, wn_f, rp_b, col_b, wn_b);
  hop2_kernel<<<NN / 4, 256, 0, stream>>>(G0, G1f, G1b,
                                          rp_f, col_f, wn_f, rp_b, col_b, wn_b);
  reorder_kernel<<<NN / 32, 256, 0, stream>>>(G0, out);
}

// Round 9
// 1030.295 us; speedup vs baseline: 1.2038x; 1.2038x over previous
//
#include <hip/hip_runtime.h>

#define NN 20000      // nodes
#define NE 320000     // edges
#define NB 8          // batch
#define NT 12         // time steps
// H = 64, OUT = 120 (5 hops x 24), G layout node-major: G[(n*NB+b)*24 + j]

typedef unsigned int u32;
typedef short bf16x8 __attribute__((ext_vector_type(8)));
typedef float f32x4 __attribute__((ext_vector_type(4)));

union U8 { u32 u[4]; bf16x8 v; };

__device__ __forceinline__ float bcast(float v, int k) {
  return __int_as_float(__builtin_amdgcn_readlane(__float_as_int(v), k));
}
// dst = { lo16 = bf16(a), hi16 = bf16(b) }  (RNE, hardware)
__device__ __forceinline__ u32 cvt_pk_bf16(float a, float b) {
  u32 r;
  asm("v_cvt_pk_bf16_f32 %0, %1, %2" : "=v"(r) : "v"(a), "v"(b));
  return r;
}
__device__ __forceinline__ float rcpf(float x) {
  float r;
  asm("v_rcp_f32 %0, %1" : "=v"(r) : "v"(x));
  return r;
}
__device__ __forceinline__ unsigned short f2bf(float f) {
  u32 u = __float_as_uint(f);
  u32 r = (u + 0x7FFFu + ((u >> 16) & 1u)) >> 16;
  return (unsigned short)r;
}
__device__ __forceinline__ float bf2f(unsigned short s) {
  return __uint_as_float(((u32)s) << 16);
}

// ---------------------------------------------------------------- degree
__global__ void deg_kernel(const int* __restrict__ ei, const float* __restrict__ ew,
                           float* __restrict__ wsum_f, float* __restrict__ wsum_b,
                           int* __restrict__ cnt_f, int* __restrict__ cnt_b) {
  int e = blockIdx.x * 256 + threadIdx.x;
  if (e >= NE) return;
  int s = ei[e], t = ei[NE + e];
  float wv = ew[e];
  atomicAdd(&wsum_f[t], wv);
  atomicAdd(&cnt_f[t], 1);
  atomicAdd(&wsum_b[s], wv);
  atomicAdd(&cnt_b[s], 1);
}

// ---------------------------------------------------------------- scan (1 block, int4)
__global__ __launch_bounds__(1024) void scan_kernel(
    const int* __restrict__ cnt_f, const int* __restrict__ cnt_b,
    int* __restrict__ rp_f, int* __restrict__ rp_b,
    int* __restrict__ cur_f, int* __restrict__ cur_b) {
  __shared__ int sm[1024];
  const int tid = threadIdx.x;
  for (int pass = 0; pass < 2; ++pass) {
    const int* cnt = pass ? cnt_b : cnt_f;
    int* rp  = pass ? rp_b  : rp_f;
    int* cur = pass ? cur_b : cur_f;
    const int base = tid * 20;
    int4 c4[5];
    int s = 0;
    if (base < NN) {
      const int4* cp = (const int4*)(cnt + base);
#pragma unroll
      for (int j = 0; j < 5; j++) c4[j] = cp[j];
#pragma unroll
      for (int j = 0; j < 5; j++) s += c4[j].x + c4[j].y + c4[j].z + c4[j].w;
    }
    __syncthreads();
    sm[tid] = s;
    __syncthreads();
    for (int off = 1; off < 1024; off <<= 1) {
      int v = (tid >= off) ? sm[tid - off] : 0;
      __syncthreads();
      sm[tid] += v;
      __syncthreads();
    }
    if (base < NN) {
      int run = sm[tid] - s;
      int4* rp4  = (int4*)(rp + base);
      int4* cur4 = (int4*)(cur + base);
#pragma unroll
      for (int j = 0; j < 5; j++) {
        int4 o;
        o.x = run; run += c4[j].x;
        o.y = run; run += c4[j].y;
        o.z = run; run += c4[j].z;
        o.w = run; run += c4[j].w;
        rp4[j] = o;
        cur4[j] = o;
      }
    }
    if (tid == 1023) rp[NN] = sm[1023];
  }
}

// ---------------------------------------------------------------- CSR fill
__global__ void fill_kernel(const int* __restrict__ ei, const float* __restrict__ ew,
                            const float* __restrict__ wsum_f, const float* __restrict__ wsum_b,
                            int* __restrict__ cur_f, int* __restrict__ cur_b,
                            int* __restrict__ col_f, float* __restrict__ wn_f,
                            int* __restrict__ col_b, float* __restrict__ wn_b) {
  int e = blockIdx.x * 256 + threadIdx.x;
  if (e >= NE) return;
  int s = ei[e], t = ei[NE + e];
  float wv = ew[e];
  int slot = atomicAdd(&cur_f[t], 1);
  float w1 = wsum_f[t];
  col_f[slot] = s;
  wn_f[slot] = (w1 > 0.f) ? wv / w1 : 0.f;
  slot = atomicAdd(&cur_b[s], 1);
  float w2 = wsum_b[s];
  col_b[slot] = t;
  wn_b[slot] = (w2 > 0.f) ? wv / w2 : 0.f;
}

// ---------------------------------------------------------------- nbq + W2 + (wcat in tail blocks)
#define NBLK_NB 313   // ceil(NN/64)
__global__ __launch_bounds__(512) void nb_kernel(
    const float* __restrict__ node_emb, const float* __restrict__ enc_b,
    const float* __restrict__ w_ih, const float* __restrict__ b_ih,
    const float* __restrict__ enc_w, const float* __restrict__ b_hh,
    const float* __restrict__ filt_w, const float* __restrict__ filt_b,
    const float* __restrict__ dec_w, const float* __restrict__ dec_b,
    float* __restrict__ nbq, float* __restrict__ W2,
    float* __restrict__ Wcat, float* __restrict__ cbv) {
  const int tid = threadIdx.x;
  if (blockIdx.x >= NBLK_NB) {
    // ---- wcat part: Wcat[64][128] = filt_w_i @ dec_w (padded), cbv
    int idx = (blockIdx.x - NBLK_NB) * 512 + tid;
    if (idx < 64 * 128) {
      int k = idx >> 7, j = idx & 127;
      float acc = 0.f;
      if (j < 120) {
        int wi = j / 24, jj = j - wi * 24;
        for (int c = 0; c < 64; c++)
          acc += filt_w[(wi * 64 + k) * 64 + c] * dec_w[c * 24 + jj];
      }
      Wcat[idx] = acc;
    } else if (idx < 64 * 128 + 24) {
      int jj = idx - 64 * 128;
      float acc = dec_b[jj];
      for (int c = 0; c < 64; c++) acc += filt_b[c] * dec_w[c * 24 + jj];
      cbv[jj] = acc;
    }
    return;
  }
  __shared__ float w3[64 * 64 * 4];
  for (int idx = tid; idx < 192 * 64; idx += 512) {
    int row = idx >> 6, k = idx & 63;
    w3[((k << 6) + (row & 63)) * 4 + (row >> 6)] = w_ih[idx];
  }
  __syncthreads();
  const int lane = tid & 63, wave = tid >> 6;
  const float4* w3v = (const float4*)w3;
  const float eb = enc_b[lane];
  const float bir = b_ih[lane], biz = b_ih[64 + lane], bin_ = b_ih[128 + lane];
  const float bhr = b_hh[lane], bhz = b_hh[64 + lane];
#pragma unroll 1
  for (int pass = 0; pass < 8; ++pass) {
    const int n = blockIdx.x * 64 + pass * 8 + wave;
    if (n >= NN) break;
    float ne = node_emb[n * 64 + lane] + eb;
    float ar = bir, az = biz, an = bin_;
#pragma unroll 16
    for (int k = 0; k < 64; k++) {
      float4 w = w3v[(k << 6) + lane];
      float nk = bcast(ne, k);
      ar = fmaf(w.x, nk, ar);
      az = fmaf(w.y, nk, az);
      an = fmaf(w.z, nk, an);
    }
    // layout: q = gt*16 + (f>>2), element f&3; fold b_hh into r,z
    nbq[(((lane >> 2)) * NN + n) * 4 + (lane & 3)]      = ar + bhr;
    nbq[((16 + (lane >> 2)) * NN + n) * 4 + (lane & 3)] = az + bhz;
    nbq[((32 + (lane >> 2)) * NN + n) * 4 + (lane & 3)] = an;
  }
  if (blockIdx.x == 0 && tid < 384) {
    int f = tid / 192, g = tid - f * 192;
    float acc = 0.f;
    for (int k2 = 0; k2 < 64; k2++) acc += enc_w[f * 64 + k2] * w_ih[g * 64 + k2];
    W2[f * 192 + g] = acc;
  }
}

// ---------------------------------------------------------------- prep: pre-built frag tables
// whh frag layout: idx = ((tile*2+ks)<<8) + (ln<<2) + r, gate=tile*16+(ln&15),
//                  k2 = ks*32 + ((ln>>4)&3)*8 + r*2
// wcat frag layout: same decode with j = tile*16+(ln&15), source Wcat[k2*128+j]
__global__ __launch_bounds__(256) void prep_kernel(
    const float* __restrict__ w_hh, const float* __restrict__ Wcat,
    u32* __restrict__ whhHi, u32* __restrict__ whhLo,
    u32* __restrict__ wcatHi, u32* __restrict__ wcatLo) {
  int idx = blockIdx.x * 256 + threadIdx.x;
  if (idx < 6144) {
    int tile = idx >> 9, ks = (idx >> 8) & 1, ln = (idx >> 2) & 63, r = idx & 3;
    int gate = tile * 16 + (ln & 15);
    int k2 = ks * 32 + ((ln >> 4) & 3) * 8 + r * 2;
    float w0 = w_hh[gate * 64 + k2];
    float w1 = w_hh[gate * 64 + k2 + 1];
    unsigned short h0 = f2bf(w0), h1 = f2bf(w1);
    whhHi[idx] = (u32)h0 | ((u32)h1 << 16);
    whhLo[idx] = (u32)f2bf(w0 - bf2f(h0)) | ((u32)f2bf(w1 - bf2f(h1)) << 16);
  } else if (idx < 6144 + 4096) {
    int e = idx - 6144;
    int tile = e >> 9, ks = (e >> 8) & 1, ln = (e >> 2) & 63, r = e & 3;
    int j = tile * 16 + (ln & 15);
    int k2 = ks * 32 + ((ln >> 4) & 3) * 8 + r * 2;
    float w0 = Wcat[k2 * 128 + j];
    float w1 = Wcat[(k2 + 1) * 128 + j];
    unsigned short h0 = f2bf(w0), h1 = f2bf(w1);
    wcatHi[e] = (u32)h0 | ((u32)h1 << 16);
    wcatLo[e] = (u32)f2bf(w0 - bf2f(h0)) | ((u32)f2bf(w1 - bf2f(h1)) << 16);
  }
}

// ---------------------------------------------------------------- MFMA GRU + MFMA epilogue
// 4 waves / 256 threads, 64 seqs/block, static LDS 24KB (6 blocks/CU):
//   [0,6144) whh-HI frags (copied from whhHi); LO frags read from GLOBAL (L1-hot 24KB)
//   h-exchange in-register via ds_bpermute:
//     producer lane (g2,sl) packs h[k=fb*16+g2*4+r][sl] into
//       hiP[fb] (r=0,1), hiQ[fb] (r=2,3), loP/loQ (lo-planes)
//     consumer lane (g,sl) frag word m of ks-half:
//       = {hiP/hiQ}[ (ks? 2:0) + (g>>1) ][m&1] @ lane (2(g&1)+(m>>1))*16+sl
//   epilogue overlays [0,4096) wcat-HI; wcat-LO from global.
#define MFMA(acc, a, b) acc = __builtin_amdgcn_mfma_f32_16x16x32_bf16((a), (b), acc, 0, 0, 0)
#define BP(addr, reg) __builtin_amdgcn_ds_bpermute((addr), (int)(reg))

__global__ __launch_bounds__(256, 4) void gru_kernel(
    const float* __restrict__ x, const float* __restrict__ nbq,
    const float* __restrict__ W2, const float* __restrict__ b_hh,
    const u32* __restrict__ whhHi, const u32* __restrict__ whhLo,
    const u32* __restrict__ wcatHi, const u32* __restrict__ wcatLo,
    const float* __restrict__ cbv,
    float* __restrict__ G0, float* __restrict__ G1f, float* __restrict__ G2f,
    float* __restrict__ G1b, float* __restrict__ G2b) {
  __shared__ __align__(16) u32 lds[6144];
  const int tid = threadIdx.x;

  // ---- stage whh-hi frags: linear uint4 copy (coalesced, conflict-free)
  for (int i = tid; i < 1536; i += 256)
    ((uint4*)lds)[i] = ((const uint4*)whhHi)[i];
  __syncthreads();

  const int lane = tid & 63, wave = tid >> 6;
  const int g = lane >> 4, sl = lane & 15;
  const int seq = blockIdx.x * 64 + wave * 16 + sl;
  const int bb = seq / NN;
  const int node = seq - bb * NN;
  // bpermute source-lane byte addresses (lane-constant)
  const int addrA = (((g & 1) * 32) + sl) * 4;
  const int addrB = addrA + 64;
  const bool fbHi = (g >= 2);

#define LDH(tile, ks) (*(const bf16x8*)(lds + (((tile) * 2 + (ks)) << 8) + (lane << 2)))
#define LDL(tile, ks) (*(const bf16x8*)(whhLo + (((tile) * 2 + (ks)) << 8) + (lane << 2)))

// build one (hb, lb) B-frag pair for k-half fo/2 (fo = 0 or 2)
#define BLD(hb, lb, fo) { \
    int a_, b_; \
    a_ = BP(addrA, hiP[fo]); b_ = BP(addrA, hiP[(fo) + 1]); hb.u[0] = fbHi ? b_ : a_; \
    a_ = BP(addrA, hiQ[fo]); b_ = BP(addrA, hiQ[(fo) + 1]); hb.u[1] = fbHi ? b_ : a_; \
    a_ = BP(addrB, hiP[fo]); b_ = BP(addrB, hiP[(fo) + 1]); hb.u[2] = fbHi ? b_ : a_; \
    a_ = BP(addrB, hiQ[fo]); b_ = BP(addrB, hiQ[(fo) + 1]); hb.u[3] = fbHi ? b_ : a_; \
    a_ = BP(addrA, loP[fo]); b_ = BP(addrA, loP[(fo) + 1]); lb.u[0] = fbHi ? b_ : a_; \
    a_ = BP(addrA, loQ[fo]); b_ = BP(addrA, loQ[(fo) + 1]); lb.u[1] = fbHi ? b_ : a_; \
    a_ = BP(addrB, loP[fo]); b_ = BP(addrB, loP[(fo) + 1]); lb.u[2] = fbHi ? b_ : a_; \
    a_ = BP(addrB, loQ[fo]); b_ = BP(addrB, loQ[(fo) + 1]); lb.u[3] = fbHi ? b_ : a_; \
  }

  // W2 (x-side) per-lane regs: lanes<16 carry k=0,1; others zero
  u32 w2h[12], w2l[12];
#pragma unroll
  for (int tl = 0; tl < 12; tl++) {
    float w0 = W2[tl * 16 + sl], w1 = W2[192 + tl * 16 + sl];
    u32 ph = cvt_pk_bf16(w0, w1);
    float lo0 = w0 - __uint_as_float(ph << 16);
    float lo1 = w1 - __uint_as_float(ph & 0xffff0000u);
    u32 pl = cvt_pk_bf16(lo0, lo1);
    w2h[tl] = (lane < 16) ? ph : 0u;
    w2l[tl] = (lane < 16) ? pl : 0u;
  }

  // acc inits: nbA=r(+bhh), nbB=z(+bhh), nbC=n(x-side), bhnv=b_hh n-part
  f32x4 nbA[4], nbB[4], nbC[4], bhnv[4];
#pragma unroll
  for (int fb = 0; fb < 4; fb++) {
    nbA[fb]  = *(const f32x4*)(nbq + ((size_t)(fb * 4 + g) * NN + node) * 4);
    nbB[fb]  = *(const f32x4*)(nbq + ((size_t)(16 + fb * 4 + g) * NN + node) * 4);
    nbC[fb]  = *(const f32x4*)(nbq + ((size_t)(32 + fb * 4 + g) * NN + node) * 4);
    bhnv[fb] = *(const f32x4*)(b_hh + 128 + fb * 16 + g * 4);
  }

  f32x4 hreg[4];
#pragma unroll
  for (int fb = 0; fb < 4; fb++) hreg[fb] = (f32x4){0.f, 0.f, 0.f, 0.f};

  // packed h exchange registers (hi/lo plane, r-pairs P=01 Q=23)
  u32 hiP[4], hiQ[4], loP[4], loQ[4];

  const float* xptr = x + ((size_t)(bb * NT) * NN + node) * 2;

  U8 hb0, hb1, lb0, lb1;

  float2 xv = *(const float2*)(xptr);

#pragma unroll 1
  for (int t = 0; t < NT; t++) {
    float2 xvn;
    if (t + 1 < NT) xvn = *(const float2*)(xptr + (size_t)(t + 1) * (NN * 2));
    // x B-frag: k01=xh, k23=xl, k45=xh (garbage in lanes g>0 is killed by A=0)
    u32 xhw = cvt_pk_bf16(xv.x, xv.y);
    float xl0 = xv.x - __uint_as_float(xhw << 16);
    float xl1 = xv.y - __uint_as_float(xhw & 0xffff0000u);
    u32 xlw = cvt_pk_bf16(xl0, xl1);
    U8 xB;
    xB.u[0] = xhw; xB.u[1] = xlw; xB.u[2] = xhw; xB.u[3] = 0u;

    if (t) { BLD(hb0, lb0, 0); BLD(hb1, lb1, 2); }

#pragma unroll
    for (int fb = 0; fb < 4; fb++) {
      f32x4 aR = nbA[fb], aZ = nbB[fb], aXN = nbC[fb], aHN = bhnv[fb];
      if (t) {
        bf16x8 Ah0 = LDH(fb, 0), Al0 = LDL(fb, 0);
        bf16x8 Ah1 = LDH(fb, 1), Al1 = LDL(fb, 1);
        MFMA(aR, Ah0, hb0.v); MFMA(aR, Ah0, lb0.v); MFMA(aR, Al0, hb0.v);
        MFMA(aR, Ah1, hb1.v); MFMA(aR, Ah1, lb1.v); MFMA(aR, Al1, hb1.v);
        bf16x8 Bh0 = LDH(4 + fb, 0), Bl0 = LDL(4 + fb, 0);
        bf16x8 Bh1 = LDH(4 + fb, 1), Bl1 = LDL(4 + fb, 1);
        MFMA(aZ, Bh0, hb0.v); MFMA(aZ, Bh0, lb0.v); MFMA(aZ, Bl0, hb0.v);
        MFMA(aZ, Bh1, hb1.v); MFMA(aZ, Bh1, lb1.v); MFMA(aZ, Bl1, hb1.v);
        bf16x8 Ch0 = LDH(8 + fb, 0), Cl0 = LDL(8 + fb, 0);
        bf16x8 Ch1 = LDH(8 + fb, 1), Cl1 = LDL(8 + fb, 1);
        MFMA(aHN, Ch0, hb0.v); MFMA(aHN, Ch0, lb0.v); MFMA(aHN, Cl0, hb0.v);
        MFMA(aHN, Ch1, hb1.v); MFMA(aHN, Ch1, lb1.v); MFMA(aHN, Cl1, hb1.v);
      }
      // x-side: one MFMA per gate (3-term split packed along K)
      U8 aW;
      aW.u[0] = w2h[fb];     aW.u[1] = w2h[fb];     aW.u[2] = w2l[fb];     aW.u[3] = 0u;
      MFMA(aR, aW.v, xB.v);
      aW.u[0] = w2h[4 + fb]; aW.u[1] = w2h[4 + fb]; aW.u[2] = w2l[4 + fb];
      MFMA(aZ, aW.v, xB.v);
      aW.u[0] = w2h[8 + fb]; aW.u[1] = w2h[8 + fb]; aW.u[2] = w2l[8 + fb];
      MFMA(aXN, aW.v, xB.v);

      // gate math (lane-local), pack h hi/lo planes into exchange regs
      float hv[4];
#pragma unroll
      for (int r = 0; r < 4; r++) {
        float rr = rcpf(1.f + __expf(-aR[r]));
        float zz = rcpf(1.f + __expf(-aZ[r]));
        float nv = fmaf(rr, aHN[r], aXN[r]);
        float th = fmaf(-2.f, rcpf(1.f + __expf(2.f * nv)), 1.f);
        float h2 = fmaf(zz, hreg[fb][r] - th, th);
        hreg[fb][r] = h2;
        hv[r] = h2;
      }
      u32 hA = cvt_pk_bf16(hv[0], hv[1]);
      u32 hB = cvt_pk_bf16(hv[2], hv[3]);
      float l0 = hv[0] - __uint_as_float(hA << 16);
      float l1 = hv[1] - __uint_as_float(hA & 0xffff0000u);
      float l2 = hv[2] - __uint_as_float(hB << 16);
      float l3 = hv[3] - __uint_as_float(hB & 0xffff0000u);
      hiP[fb] = hA;
      hiQ[fb] = hB;
      loP[fb] = cvt_pk_bf16(l0, l1);
      loQ[fb] = cvt_pk_bf16(l2, l3);
    }
    xv = xvn;
  }

  // ---- epilogue: out120 = h @ Wcat (3-term split MFMA; hi from LDS, lo global)
  __syncthreads();   // all waves done with whh-hi frag region
  for (int i = tid; i < 1024; i += 256)
    ((uint4*)lds)[i] = ((const uint4*)wcatHi)[i];
  __syncthreads();
  BLD(hb0, lb0, 0); BLD(hb1, lb1, 2);

#define LCH(tile, ks) (*(const bf16x8*)(lds + (((tile) * 2 + (ks)) << 8) + (lane << 2)))
#define LCL(tile, ks) (*(const bf16x8*)(wcatLo + (((tile) * 2 + (ks)) << 8) + (lane << 2)))
#pragma unroll
  for (int tile = 0; tile < 8; tile++) {
    f32x4 acc = (f32x4){0.f, 0.f, 0.f, 0.f};
    bf16x8 Ah0 = LCH(tile, 0), Al0 = LCL(tile, 0);
    MFMA(acc, Ah0, hb0.v); MFMA(acc, Ah0, lb0.v); MFMA(acc, Al0, hb0.v);
    bf16x8 Ah1 = LCH(tile, 1), Al1 = LCL(tile, 1);
    MFMA(acc, Ah1, hb1.v); MFMA(acc, Ah1, lb1.v); MFMA(acc, Al1, hb1.v);
#pragma unroll
    for (int r = 0; r < 4; r++) {
      int j = tile * 16 + g * 4 + r;
      if (j < 120) {
        int wi = j / 24, jj = j - wi * 24;
        float val = acc[r];
        if (wi == 0) val += cbv[jj];
        float* gb = (wi == 0) ? G0 : (wi == 1) ? G1f : (wi == 2) ? G2f : (wi == 3) ? G1b : G2b;
        gb[((size_t)node * NB + bb) * 24 + jj] = val;   // node-major
      }
    }
  }
}

// ---------------------------------------------------------------- hop1: G1f += Pf G2f | G1b += Pb G2b
// one wave per (n, dir); lanes 0-47 hold the 192-float row as float4
__global__ __launch_bounds__(256) void hop1_kernel(
    float* __restrict__ G1f, const float* __restrict__ G2f,
    float* __restrict__ G1b, const float* __restrict__ G2b,
    const int* __restrict__ rp_f, const int* __restrict__ col_f, const float* __restrict__ wn_f,
    const int* __restrict__ rp_b, const int* __restrict__ col_b, const float* __restrict__ wn_b) {
  const int wv = threadIdx.x >> 6;
  const int lane = threadIdx.x & 63;
  const int task = blockIdx.x * 4 + wv;
  const int fwd = task < NN;
  const int n = fwd ? task : task - NN;
  const int* rp  = fwd ? rp_f : rp_b;
  const int* col = fwd ? col_f : col_b;
  const float* wn = fwd ? wn_f : wn_b;
  const float4* src = (const float4*)(fwd ? G2f : G2b);
  float4* dst = (float4*)(fwd ? G1f : G1b);
  const int e0 = rp[n], e1 = rp[n + 1];
  if (lane >= 48) return;
  float4 acc = {0.f, 0.f, 0.f, 0.f};
  for (int e = e0; e < e1; ++e) {
    const int c = col[e];
    const float w = wn[e];
    float4 v = src[(size_t)c * 48 + lane];
    acc.x = fmaf(w, v.x, acc.x);
    acc.y = fmaf(w, v.y, acc.y);
    acc.z = fmaf(w, v.z, acc.z);
    acc.w = fmaf(w, v.w, acc.w);
  }
  float4 d = dst[(size_t)n * 48 + lane];
  d.x += acc.x; d.y += acc.y; d.z += acc.z; d.w += acc.w;
  dst[(size_t)n * 48 + lane] = d;
}

// ---------------------------------------------------------------- hop2: G0 += Pf G1f + Pb G1b
__global__ __launch_bounds__(256) void hop2_kernel(
    float* __restrict__ G0, const float* __restrict__ G1f, const float* __restrict__ G1b,
    const int* __restrict__ rp_f, const int* __restrict__ col_f, const float* __restrict__ wn_f,
    const int* __restrict__ rp_b, const int* __restrict__ col_b, const float* __restrict__ wn_b) {
  const int wv = threadIdx.x >> 6;
  const int lane = threadIdx.x & 63;
  const int n = blockIdx.x * 4 + wv;
  if (lane >= 48) return;
  const float4* s1 = (const float4*)G1f;
  const float4* s2 = (const float4*)G1b;
  float4* dst = (float4*)G0;
  float4 acc = dst[(size_t)n * 48 + lane];
  int e0 = rp_f[n], e1 = rp_f[n + 1];
  for (int e = e0; e < e1; ++e) {
    const int c = col_f[e];
    const float w = wn_f[e];
    float4 v = s1[(size_t)c * 48 + lane];
    acc.x = fmaf(w, v.x, acc.x);
    acc.y = fmaf(w, v.y, acc.y);
    acc.z = fmaf(w, v.z, acc.z);
    acc.w = fmaf(w, v.w, acc.w);
  }
  e0 = rp_b[n]; e1 = rp_b[n + 1];
  for (int e = e0; e < e1; ++e) {
    const int c = col_b[e];
    const float w = wn_b[e];
    float4 v = s2[(size_t)c * 48 + lane];
    acc.x = fmaf(w, v.x, acc.x);
    acc.y = fmaf(w, v.y, acc.y);
    acc.z = fmaf(w, v.z, acc.z);
    acc.w = fmaf(w, v.w, acc.w);
  }
  dst[(size_t)n * 48 + lane] = acc;
}

// ---------------------------------------------------------------- G0[n][b][24] -> out[b][t][n][f]
__global__ __launch_bounds__(256) void reorder_kernel(const float* __restrict__ G0,
                                                      float* __restrict__ out) {
  __shared__ float tile[32 * 193];
  const int n0 = blockIdx.x * 32;
  const int tid = threadIdx.x;
  for (int idx = tid; idx < 6144; idx += 256) {
    int i = idx / 192, r = idx - i * 192;
    tile[i * 193 + r] = G0[(size_t)n0 * 192 + idx];
  }
  __syncthreads();
  for (int idx = tid; idx < 6144; idx += 256) {
    int b = idx / 768;
    int rem = idx - b * 768;
    int t = rem >> 6;
    int rem2 = rem & 63;
    int i = rem2 >> 1, f = rem2 & 1;
    out[(((size_t)b * NT + t) * NN + n0 + i) * 2 + f] = tile[i * 193 + b * 24 + t * 2 + f];
  }
}

// ----------------------------------------------------------------
extern "C" void kernel_launch(void* const* d_in, const int* in_sizes, int n_in,
                              void* d_out, int out_size, void* d_ws, size_t ws_size,
                              hipStream_t stream) {
  const float* x        = (const float*)d_in[0];
  const int*   ei       = (const int*)d_in[1];
  const float* ew       = (const float*)d_in[2];
  const float* enc_w    = (const float*)d_in[3];
  const float* enc_b    = (const float*)d_in[4];
  const float* node_emb = (const float*)d_in[5];
  const float* w_ih     = (const float*)d_in[6];
  const float* w_hh     = (const float*)d_in[7];
  const float* b_ih     = (const float*)d_in[8];
  const float* b_hh     = (const float*)d_in[9];
  const float* filt_w   = (const float*)d_in[10];
  const float* filt_b   = (const float*)d_in[11];
  const float* dec_w    = (const float*)d_in[12];
  const float* dec_b    = (const float*)d_in[13];
  float* out = (float*)d_out;

  char* p = (char*)d_ws;
  auto alloc = [&](size_t bytes) {
    char* r = p;
    p += (bytes + 255) & ~(size_t)255;
    return r;
  };
  const size_t BN24 = (size_t)NB * NN * 24;
  float* G0   = (float*)alloc(BN24 * 4);
  float* G1f  = (float*)alloc(BN24 * 4);
  float* G2f  = (float*)alloc(BN24 * 4);
  float* G1b  = (float*)alloc(BN24 * 4);
  float* G2b  = (float*)alloc(BN24 * 4);
  float* nbq  = (float*)alloc((size_t)NN * 192 * 4);
  int* rp_f   = (int*)alloc((NN + 1) * 4);
  int* rp_b   = (int*)alloc((NN + 1) * 4);
  char* zreg  = alloc(4 * NN * 4);        // wsum_f, wsum_b, cnt_f, cnt_b (zeroed)
  float* wsum_f = (float*)zreg;
  float* wsum_b = wsum_f + NN;
  int*   cnt_f  = (int*)(wsum_b + NN);
  int*   cnt_b  = cnt_f + NN;
  int* cur_f  = (int*)alloc(NN * 4);
  int* cur_b  = (int*)alloc(NN * 4);
  int* col_f  = (int*)alloc((size_t)NE * 4);
  float* wn_f = (float*)alloc((size_t)NE * 4);
  int* col_b  = (int*)alloc((size_t)NE * 4);
  float* wn_b = (float*)alloc((size_t)NE * 4);
  float* Wcat = (float*)alloc(64 * 128 * 4);
  float* cbv  = (float*)alloc(32 * 4);
  float* W2   = (float*)alloc(384 * 4);
  u32* whhHi  = (u32*)alloc(6144 * 4);
  u32* whhLo  = (u32*)alloc(6144 * 4);
  u32* wcatHi = (u32*)alloc(4096 * 4);
  u32* wcatLo = (u32*)alloc(4096 * 4);

  hipMemsetAsync(zreg, 0, 4 * NN * 4, stream);
  deg_kernel<<<(NE + 255) / 256, 256, 0, stream>>>(ei, ew, wsum_f, wsum_b, cnt_f, cnt_b);
  scan_kernel<<<1, 1024, 0, stream>>>(cnt_f, cnt_b, rp_f, rp_b, cur_f, cur_b);
  fill_kernel<<<(NE + 255) / 256, 256, 0, stream>>>(ei, ew, wsum_f, wsum_b, cur_f, cur_b,
                                                    col_f, wn_f, col_b, wn_b);
  nb_kernel<<<NBLK_NB + 17, 512, 0, stream>>>(node_emb, enc_b, w_ih, b_ih, enc_w, b_hh,
                                              filt_w, filt_b, dec_w, dec_b,
                                              nbq, W2, Wcat, cbv);
  prep_kernel<<<40, 256, 0, stream>>>(w_hh, Wcat, whhHi, whhLo, wcatHi, wcatLo);
  gru_kernel<<<(NB * NN) / 64, 256, 0, stream>>>(x, nbq, W2, b_hh,
                                                 whhHi, whhLo, wcatHi, wcatLo, cbv,
                                                 G0, G1f, G2f, G1b, G2b);
  hop1_kernel<<<2 * NN / 4, 256, 0, stream>>>(G1f, G2f, G1b, G2b,
                                              rp_f, col_f, wn_f, rp_b, col_b, wn_b);
  hop2_kernel<<<NN / 4, 256, 0, stream>>>(G0, G1f, G1b,
                                          rp_f, col_f, wn_f, rp_b, col_b, wn_b);
  reorder_kernel<<<NN / 32, 256, 0, stream>>>(G0, out);
}

// Round 10
// 558.560 us; speedup vs baseline: 2.2205x; 1.8446x over previous
//
#include <hip/hip_runtime.h>

#define NN 20000      // nodes
#define NE 320000     // edges
#define NB 8          // batch
#define NT 12         // time steps
// H = 64, OUT = 120 (5 hops x 24), G layout node-major: G[(n*NB+b)*24 + j]

typedef unsigned int u32;
typedef short bf16x8 __attribute__((ext_vector_type(8)));
typedef float f32x4 __attribute__((ext_vector_type(4)));

union U8 { u32 u[4]; bf16x8 v; };

__device__ __forceinline__ float bcast(float v, int k) {
  return __int_as_float(__builtin_amdgcn_readlane(__float_as_int(v), k));
}
// dst = { lo16 = bf16(a), hi16 = bf16(b) }  (RNE, hardware)
__device__ __forceinline__ u32 cvt_pk_bf16(float a, float b) {
  u32 r;
  asm("v_cvt_pk_bf16_f32 %0, %1, %2" : "=v"(r) : "v"(a), "v"(b));
  return r;
}
__device__ __forceinline__ float rcpf(float x) {
  float r;
  asm("v_rcp_f32 %0, %1" : "=v"(r) : "v"(x));
  return r;
}
__device__ __forceinline__ unsigned short f2bf(float f) {
  u32 u = __float_as_uint(f);
  u32 r = (u + 0x7FFFu + ((u >> 16) & 1u)) >> 16;
  return (unsigned short)r;
}
__device__ __forceinline__ float bf2f(unsigned short s) {
  return __uint_as_float(((u32)s) << 16);
}

// ---------------------------------------------------------------- degree
__global__ void deg_kernel(const int* __restrict__ ei, const float* __restrict__ ew,
                           float* __restrict__ wsum_f, float* __restrict__ wsum_b,
                           int* __restrict__ cnt_f, int* __restrict__ cnt_b) {
  int e = blockIdx.x * 256 + threadIdx.x;
  if (e >= NE) return;
  int s = ei[e], t = ei[NE + e];
  float wv = ew[e];
  atomicAdd(&wsum_f[t], wv);
  atomicAdd(&cnt_f[t], 1);
  atomicAdd(&wsum_b[s], wv);
  atomicAdd(&cnt_b[s], 1);
}

// ---------------------------------------------------------------- scan (1 block, int4)
__global__ __launch_bounds__(1024) void scan_kernel(
    const int* __restrict__ cnt_f, const int* __restrict__ cnt_b,
    int* __restrict__ rp_f, int* __restrict__ rp_b,
    int* __restrict__ cur_f, int* __restrict__ cur_b) {
  __shared__ int sm[1024];
  const int tid = threadIdx.x;
  for (int pass = 0; pass < 2; ++pass) {
    const int* cnt = pass ? cnt_b : cnt_f;
    int* rp  = pass ? rp_b  : rp_f;
    int* cur = pass ? cur_b : cur_f;
    const int base = tid * 20;
    int4 c4[5];
    int s = 0;
    if (base < NN) {
      const int4* cp = (const int4*)(cnt + base);
#pragma unroll
      for (int j = 0; j < 5; j++) c4[j] = cp[j];
#pragma unroll
      for (int j = 0; j < 5; j++) s += c4[j].x + c4[j].y + c4[j].z + c4[j].w;
    }
    __syncthreads();
    sm[tid] = s;
    __syncthreads();
    for (int off = 1; off < 1024; off <<= 1) {
      int v = (tid >= off) ? sm[tid - off] : 0;
      __syncthreads();
      sm[tid] += v;
      __syncthreads();
    }
    if (base < NN) {
      int run = sm[tid] - s;
      int4* rp4  = (int4*)(rp + base);
      int4* cur4 = (int4*)(cur + base);
#pragma unroll
      for (int j = 0; j < 5; j++) {
        int4 o;
        o.x = run; run += c4[j].x;
        o.y = run; run += c4[j].y;
        o.z = run; run += c4[j].z;
        o.w = run; run += c4[j].w;
        rp4[j] = o;
        cur4[j] = o;
      }
    }
    if (tid == 1023) rp[NN] = sm[1023];
  }
}

// ---------------------------------------------------------------- CSR fill
__global__ void fill_kernel(const int* __restrict__ ei, const float* __restrict__ ew,
                            const float* __restrict__ wsum_f, const float* __restrict__ wsum_b,
                            int* __restrict__ cur_f, int* __restrict__ cur_b,
                            int* __restrict__ col_f, float* __restrict__ wn_f,
                            int* __restrict__ col_b, float* __restrict__ wn_b) {
  int e = blockIdx.x * 256 + threadIdx.x;
  if (e >= NE) return;
  int s = ei[e], t = ei[NE + e];
  float wv = ew[e];
  int slot = atomicAdd(&cur_f[t], 1);
  float w1 = wsum_f[t];
  col_f[slot] = s;
  wn_f[slot] = (w1 > 0.f) ? wv / w1 : 0.f;
  slot = atomicAdd(&cur_b[s], 1);
  float w2 = wsum_b[s];
  col_b[slot] = t;
  wn_b[slot] = (w2 > 0.f) ? wv / w2 : 0.f;
}

// ---------------------------------------------------------------- nbq + W2 + (wcat in tail blocks)
#define NBLK_NB 313   // ceil(NN/64)
__global__ __launch_bounds__(512) void nb_kernel(
    const float* __restrict__ node_emb, const float* __restrict__ enc_b,
    const float* __restrict__ w_ih, const float* __restrict__ b_ih,
    const float* __restrict__ enc_w, const float* __restrict__ b_hh,
    const float* __restrict__ filt_w, const float* __restrict__ filt_b,
    const float* __restrict__ dec_w, const float* __restrict__ dec_b,
    float* __restrict__ nbq, float* __restrict__ W2,
    float* __restrict__ Wcat, float* __restrict__ cbv) {
  const int tid = threadIdx.x;
  if (blockIdx.x >= NBLK_NB) {
    // ---- wcat part: Wcat[64][128] = filt_w_i @ dec_w (padded), cbv
    int idx = (blockIdx.x - NBLK_NB) * 512 + tid;
    if (idx < 64 * 128) {
      int k = idx >> 7, j = idx & 127;
      float acc = 0.f;
      if (j < 120) {
        int wi = j / 24, jj = j - wi * 24;
        for (int c = 0; c < 64; c++)
          acc += filt_w[(wi * 64 + k) * 64 + c] * dec_w[c * 24 + jj];
      }
      Wcat[idx] = acc;
    } else if (idx < 64 * 128 + 24) {
      int jj = idx - 64 * 128;
      float acc = dec_b[jj];
      for (int c = 0; c < 64; c++) acc += filt_b[c] * dec_w[c * 24 + jj];
      cbv[jj] = acc;
    }
    return;
  }
  __shared__ float w3[64 * 64 * 4];
  for (int idx = tid; idx < 192 * 64; idx += 512) {
    int row = idx >> 6, k = idx & 63;
    w3[((k << 6) + (row & 63)) * 4 + (row >> 6)] = w_ih[idx];
  }
  __syncthreads();
  const int lane = tid & 63, wave = tid >> 6;
  const float4* w3v = (const float4*)w3;
  const float eb = enc_b[lane];
  const float bir = b_ih[lane], biz = b_ih[64 + lane], bin_ = b_ih[128 + lane];
  const float bhr = b_hh[lane], bhz = b_hh[64 + lane];
#pragma unroll 1
  for (int pass = 0; pass < 8; ++pass) {
    const int n = blockIdx.x * 64 + pass * 8 + wave;
    if (n >= NN) break;
    float ne = node_emb[n * 64 + lane] + eb;
    float ar = bir, az = biz, an = bin_;
#pragma unroll 16
    for (int k = 0; k < 64; k++) {
      float4 w = w3v[(k << 6) + lane];
      float nk = bcast(ne, k);
      ar = fmaf(w.x, nk, ar);
      az = fmaf(w.y, nk, az);
      an = fmaf(w.z, nk, an);
    }
    // layout: q = gt*16 + (f>>2), element f&3; fold b_hh into r,z
    nbq[(((lane >> 2)) * NN + n) * 4 + (lane & 3)]      = ar + bhr;
    nbq[((16 + (lane >> 2)) * NN + n) * 4 + (lane & 3)] = az + bhz;
    nbq[((32 + (lane >> 2)) * NN + n) * 4 + (lane & 3)] = an;
  }
  if (blockIdx.x == 0 && tid < 384) {
    int f = tid / 192, g = tid - f * 192;
    float acc = 0.f;
    for (int k2 = 0; k2 < 64; k2++) acc += enc_w[f * 64 + k2] * w_ih[g * 64 + k2];
    W2[f * 192 + g] = acc;
  }
}

// ---------------------------------------------------------------- MFMA GRU + MFMA epilogue
// 4 waves / 256 threads, 64 seqs/block, static LDS 48KB (u32 idx):
//   [0,6144) whh-hi frags; [6144,12288) whh-lo frags   (3 blocks/CU)
//   h-exchange is IN-REGISTER via ds_bpermute (no LDS space):
//     producer lane (g2,sl) packs h[k=fb*16+g2*4+r][sl] into
//       hiP[fb] (r=0,1), hiQ[fb] (r=2,3), loP/loQ (lo-planes)
//     consumer lane (g,sl) frag word m of ks-half:
//       = {hiP/hiQ}[ (ks? 2:0) + (g>>1) ][m&1] @ lane (2(g&1)+(m>>1))*16+sl
//   epilogue overlays [0,4096) wcat-hi, [4096,8192) wcat-lo.
#define MFMA(acc, a, b) acc = __builtin_amdgcn_mfma_f32_16x16x32_bf16((a), (b), acc, 0, 0, 0)
#define BP(addr, reg) __builtin_amdgcn_ds_bpermute((addr), (int)(reg))

__global__ __launch_bounds__(256, 3) void gru_kernel(
    const float* __restrict__ x, const float* __restrict__ nbq,
    const float* __restrict__ W2, const float* __restrict__ b_hh,
    const float* __restrict__ w_hh, const float* __restrict__ Wcat,
    const float* __restrict__ cbv,
    float* __restrict__ G0, float* __restrict__ G1f, float* __restrict__ G2f,
    float* __restrict__ G1b, float* __restrict__ G2b) {
  __shared__ u32 lds[12288];
  const int tid = threadIdx.x;

  // ---- whh hi/lo A-frag tables, idx-major (conflict-free stores)
  for (int idx = tid; idx < 6144; idx += 256) {
    int tile = idx >> 9, ks = (idx >> 8) & 1, ln = (idx >> 2) & 63, r = idx & 3;
    int gate = tile * 16 + (ln & 15);
    int k2 = ks * 32 + ((ln >> 4) & 3) * 8 + r * 2;
    float w0 = w_hh[gate * 64 + k2];
    float w1 = w_hh[gate * 64 + k2 + 1];
    unsigned short h0 = f2bf(w0), h1 = f2bf(w1);
    unsigned short l0 = f2bf(w0 - bf2f(h0)), l1 = f2bf(w1 - bf2f(h1));
    lds[idx]        = (u32)h0 | ((u32)h1 << 16);
    lds[6144 + idx] = (u32)l0 | ((u32)l1 << 16);
  }
  __syncthreads();

  const int lane = tid & 63, wave = tid >> 6;
  const int g = lane >> 4, sl = lane & 15;
  const int seq = blockIdx.x * 64 + wave * 16 + sl;
  const int bb = seq / NN;
  const int node = seq - bb * NN;
  // bpermute source-lane byte addresses (lane-constant)
  const int addrA = (((g & 1) * 32) + sl) * 4;
  const int addrB = addrA + 64;
  const bool fbHi = (g >= 2);

#define LDW(tile, ks, part) (*(const bf16x8*)(lds + (part) * 6144 + (((tile) * 2 + (ks)) << 8) + (lane << 2)))

// build one (hb, lb) B-frag pair for k-half fo/2 (fo = 0 or 2)
#define BLD(hb, lb, fo) { \
    int a_, b_; \
    a_ = BP(addrA, hiP[fo]); b_ = BP(addrA, hiP[(fo) + 1]); hb.u[0] = fbHi ? b_ : a_; \
    a_ = BP(addrA, hiQ[fo]); b_ = BP(addrA, hiQ[(fo) + 1]); hb.u[1] = fbHi ? b_ : a_; \
    a_ = BP(addrB, hiP[fo]); b_ = BP(addrB, hiP[(fo) + 1]); hb.u[2] = fbHi ? b_ : a_; \
    a_ = BP(addrB, hiQ[fo]); b_ = BP(addrB, hiQ[(fo) + 1]); hb.u[3] = fbHi ? b_ : a_; \
    a_ = BP(addrA, loP[fo]); b_ = BP(addrA, loP[(fo) + 1]); lb.u[0] = fbHi ? b_ : a_; \
    a_ = BP(addrA, loQ[fo]); b_ = BP(addrA, loQ[(fo) + 1]); lb.u[1] = fbHi ? b_ : a_; \
    a_ = BP(addrB, loP[fo]); b_ = BP(addrB, loP[(fo) + 1]); lb.u[2] = fbHi ? b_ : a_; \
    a_ = BP(addrB, loQ[fo]); b_ = BP(addrB, loQ[(fo) + 1]); lb.u[3] = fbHi ? b_ : a_; \
  }

  // W2 (x-side) per-lane regs: lanes<16 carry k=0,1; others zero
  u32 w2h[12], w2l[12];
#pragma unroll
  for (int tl = 0; tl < 12; tl++) {
    float w0 = W2[tl * 16 + sl], w1 = W2[192 + tl * 16 + sl];
    u32 ph = cvt_pk_bf16(w0, w1);
    float lo0 = w0 - __uint_as_float(ph << 16);
    float lo1 = w1 - __uint_as_float(ph & 0xffff0000u);
    u32 pl = cvt_pk_bf16(lo0, lo1);
    w2h[tl] = (lane < 16) ? ph : 0u;
    w2l[tl] = (lane < 16) ? pl : 0u;
  }

  // acc inits: nbA=r(+bhh), nbB=z(+bhh), nbC=n(x-side), bhnv=b_hh n-part
  f32x4 nbA[4], nbB[4], nbC[4], bhnv[4];
#pragma unroll
  for (int fb = 0; fb < 4; fb++) {
    nbA[fb]  = *(const f32x4*)(nbq + ((size_t)(fb * 4 + g) * NN + node) * 4);
    nbB[fb]  = *(const f32x4*)(nbq + ((size_t)(16 + fb * 4 + g) * NN + node) * 4);
    nbC[fb]  = *(const f32x4*)(nbq + ((size_t)(32 + fb * 4 + g) * NN + node) * 4);
    bhnv[fb] = *(const f32x4*)(b_hh + 128 + fb * 16 + g * 4);
  }

  f32x4 hreg[4];
#pragma unroll
  for (int fb = 0; fb < 4; fb++) hreg[fb] = (f32x4){0.f, 0.f, 0.f, 0.f};

  // packed h exchange registers (hi/lo plane, r-pairs P=01 Q=23)
  u32 hiP[4], hiQ[4], loP[4], loQ[4];

  const float* xptr = x + ((size_t)(bb * NT) * NN + node) * 2;

  U8 hb0, hb1, lb0, lb1;

  float2 xv = *(const float2*)(xptr);

#pragma unroll 1
  for (int t = 0; t < NT; t++) {
    float2 xvn;
    if (t + 1 < NT) xvn = *(const float2*)(xptr + (size_t)(t + 1) * (NN * 2));
    // x B-frag: k01=xh, k23=xl, k45=xh (garbage in lanes g>0 is killed by A=0)
    u32 xhw = cvt_pk_bf16(xv.x, xv.y);
    float xl0 = xv.x - __uint_as_float(xhw << 16);
    float xl1 = xv.y - __uint_as_float(xhw & 0xffff0000u);
    u32 xlw = cvt_pk_bf16(xl0, xl1);
    U8 xB;
    xB.u[0] = xhw; xB.u[1] = xlw; xB.u[2] = xhw; xB.u[3] = 0u;

    if (t) { BLD(hb0, lb0, 0); BLD(hb1, lb1, 2); }

#pragma unroll
    for (int fb = 0; fb < 4; fb++) {
      f32x4 aR = nbA[fb], aZ = nbB[fb], aXN = nbC[fb], aHN = bhnv[fb];
      if (t) {
        bf16x8 Ah0 = LDW(fb, 0, 0), Al0 = LDW(fb, 0, 1);
        bf16x8 Ah1 = LDW(fb, 1, 0), Al1 = LDW(fb, 1, 1);
        MFMA(aR, Ah0, hb0.v); MFMA(aR, Ah0, lb0.v); MFMA(aR, Al0, hb0.v);
        MFMA(aR, Ah1, hb1.v); MFMA(aR, Ah1, lb1.v); MFMA(aR, Al1, hb1.v);
        bf16x8 Bh0 = LDW(4 + fb, 0, 0), Bl0 = LDW(4 + fb, 0, 1);
        bf16x8 Bh1 = LDW(4 + fb, 1, 0), Bl1 = LDW(4 + fb, 1, 1);
        MFMA(aZ, Bh0, hb0.v); MFMA(aZ, Bh0, lb0.v); MFMA(aZ, Bl0, hb0.v);
        MFMA(aZ, Bh1, hb1.v); MFMA(aZ, Bh1, lb1.v); MFMA(aZ, Bl1, hb1.v);
        bf16x8 Ch0 = LDW(8 + fb, 0, 0), Cl0 = LDW(8 + fb, 0, 1);
        bf16x8 Ch1 = LDW(8 + fb, 1, 0), Cl1 = LDW(8 + fb, 1, 1);
        MFMA(aHN, Ch0, hb0.v); MFMA(aHN, Ch0, lb0.v); MFMA(aHN, Cl0, hb0.v);
        MFMA(aHN, Ch1, hb1.v); MFMA(aHN, Ch1, lb1.v); MFMA(aHN, Cl1, hb1.v);
      }
      // x-side: one MFMA per gate (3-term split packed along K)
      U8 aW;
      aW.u[0] = w2h[fb];     aW.u[1] = w2h[fb];     aW.u[2] = w2l[fb];     aW.u[3] = 0u;
      MFMA(aR, aW.v, xB.v);
      aW.u[0] = w2h[4 + fb]; aW.u[1] = w2h[4 + fb]; aW.u[2] = w2l[4 + fb];
      MFMA(aZ, aW.v, xB.v);
      aW.u[0] = w2h[8 + fb]; aW.u[1] = w2h[8 + fb]; aW.u[2] = w2l[8 + fb];
      MFMA(aXN, aW.v, xB.v);

      // gate math (lane-local), pack h hi/lo planes into exchange regs
      float hv[4];
#pragma unroll
      for (int r = 0; r < 4; r++) {
        float rr = rcpf(1.f + __expf(-aR[r]));
        float zz = rcpf(1.f + __expf(-aZ[r]));
        float nv = fmaf(rr, aHN[r], aXN[r]);
        float th = fmaf(-2.f, rcpf(1.f + __expf(2.f * nv)), 1.f);
        float h2 = fmaf(zz, hreg[fb][r] - th, th);
        hreg[fb][r] = h2;
        hv[r] = h2;
      }
      u32 hA = cvt_pk_bf16(hv[0], hv[1]);
      u32 hB = cvt_pk_bf16(hv[2], hv[3]);
      float l0 = hv[0] - __uint_as_float(hA << 16);
      float l1 = hv[1] - __uint_as_float(hA & 0xffff0000u);
      float l2 = hv[2] - __uint_as_float(hB << 16);
      float l3 = hv[3] - __uint_as_float(hB & 0xffff0000u);
      hiP[fb] = hA;
      hiQ[fb] = hB;
      loP[fb] = cvt_pk_bf16(l0, l1);
      loQ[fb] = cvt_pk_bf16(l2, l3);
    }
    xv = xvn;
  }

  // ---- epilogue: out120 = h @ Wcat (3-term split MFMA)
  __syncthreads();   // all waves done with whh frag region
  for (int idx = tid; idx < 4096; idx += 256) {
    int tile = idx >> 9, ks = (idx >> 8) & 1, ln = (idx >> 2) & 63, r = idx & 3;
    int j = tile * 16 + (ln & 15);
    int k2 = ks * 32 + ((ln >> 4) & 3) * 8 + r * 2;
    float w0 = Wcat[k2 * 128 + j];
    float w1 = Wcat[(k2 + 1) * 128 + j];
    unsigned short h0 = f2bf(w0), h1 = f2bf(w1);
    unsigned short l0 = f2bf(w0 - bf2f(h0)), l1 = f2bf(w1 - bf2f(h1));
    lds[idx]        = (u32)h0 | ((u32)h1 << 16);
    lds[4096 + idx] = (u32)l0 | ((u32)l1 << 16);
  }
  __syncthreads();
  BLD(hb0, lb0, 0); BLD(hb1, lb1, 2);

#define LDC(tile, ks, part) (*(const bf16x8*)(lds + (part) * 4096 + (((tile) * 2 + (ks)) << 8) + (lane << 2)))
#pragma unroll
  for (int tile = 0; tile < 8; tile++) {
    f32x4 acc = (f32x4){0.f, 0.f, 0.f, 0.f};
    bf16x8 Ah0 = LDC(tile, 0, 0), Al0 = LDC(tile, 0, 1);
    MFMA(acc, Ah0, hb0.v); MFMA(acc, Ah0, lb0.v); MFMA(acc, Al0, hb0.v);
    bf16x8 Ah1 = LDC(tile, 1, 0), Al1 = LDC(tile, 1, 1);
    MFMA(acc, Ah1, hb1.v); MFMA(acc, Ah1, lb1.v); MFMA(acc, Al1, hb1.v);
#pragma unroll
    for (int r = 0; r < 4; r++) {
      int j = tile * 16 + g * 4 + r;
      if (j < 120) {
        int wi = j / 24, jj = j - wi * 24;
        float val = acc[r];
        if (wi == 0) val += cbv[jj];
        float* gb = (wi == 0) ? G0 : (wi == 1) ? G1f : (wi == 2) ? G2f : (wi == 3) ? G1b : G2b;
        gb[((size_t)node * NB + bb) * 24 + jj] = val;   // node-major
      }
    }
  }
}

// ---------------------------------------------------------------- hop1: G1f += Pf G2f | G1b += Pb G2b
// one wave per (n, dir); lanes 0-47 hold the 192-float row as float4; unroll-2
__global__ __launch_bounds__(256) void hop1_kernel(
    float* __restrict__ G1f, const float* __restrict__ G2f,
    float* __restrict__ G1b, const float* __restrict__ G2b,
    const int* __restrict__ rp_f, const int* __restrict__ col_f, const float* __restrict__ wn_f,
    const int* __restrict__ rp_b, const int* __restrict__ col_b, const float* __restrict__ wn_b) {
  const int wv = threadIdx.x >> 6;
  const int lane = threadIdx.x & 63;
  const int task = blockIdx.x * 4 + wv;
  const int fwd = task < NN;
  const int n = fwd ? task : task - NN;
  const int* rp  = fwd ? rp_f : rp_b;
  const int* col = fwd ? col_f : col_b;
  const float* wn = fwd ? wn_f : wn_b;
  const float4* src = (const float4*)(fwd ? G2f : G2b);
  float4* dst = (float4*)(fwd ? G1f : G1b);
  const int e0 = rp[n], e1 = rp[n + 1];
  if (lane >= 48) return;
  float4 acc0 = {0.f, 0.f, 0.f, 0.f};
  float4 acc1 = {0.f, 0.f, 0.f, 0.f};
  int e = e0;
  for (; e + 1 < e1; e += 2) {
    const int c0 = col[e], c1 = col[e + 1];
    const float w0 = wn[e], w1 = wn[e + 1];
    float4 v0 = src[(size_t)c0 * 48 + lane];
    float4 v1 = src[(size_t)c1 * 48 + lane];
    acc0.x = fmaf(w0, v0.x, acc0.x); acc1.x = fmaf(w1, v1.x, acc1.x);
    acc0.y = fmaf(w0, v0.y, acc0.y); acc1.y = fmaf(w1, v1.y, acc1.y);
    acc0.z = fmaf(w0, v0.z, acc0.z); acc1.z = fmaf(w1, v1.z, acc1.z);
    acc0.w = fmaf(w0, v0.w, acc0.w); acc1.w = fmaf(w1, v1.w, acc1.w);
  }
  if (e < e1) {
    const int c0 = col[e];
    const float w0 = wn[e];
    float4 v0 = src[(size_t)c0 * 48 + lane];
    acc0.x = fmaf(w0, v0.x, acc0.x);
    acc0.y = fmaf(w0, v0.y, acc0.y);
    acc0.z = fmaf(w0, v0.z, acc0.z);
    acc0.w = fmaf(w0, v0.w, acc0.w);
  }
  float4 d = dst[(size_t)n * 48 + lane];
  d.x += acc0.x + acc1.x;
  d.y += acc0.y + acc1.y;
  d.z += acc0.z + acc1.z;
  d.w += acc0.w + acc1.w;
  dst[(size_t)n * 48 + lane] = d;
}

// ---------------------------------------------------------------- hop2: G0 += Pf G1f + Pb G1b (unroll-2)
__global__ __launch_bounds__(256) void hop2_kernel(
    float* __restrict__ G0, const float* __restrict__ G1f, const float* __restrict__ G1b,
    const int* __restrict__ rp_f, const int* __restrict__ col_f, const float* __restrict__ wn_f,
    const int* __restrict__ rp_b, const int* __restrict__ col_b, const float* __restrict__ wn_b) {
  const int wv = threadIdx.x >> 6;
  const int lane = threadIdx.x & 63;
  const int n = blockIdx.x * 4 + wv;
  if (lane >= 48) return;
  const float4* s1 = (const float4*)G1f;
  const float4* s2 = (const float4*)G1b;
  float4* dst = (float4*)G0;
  float4 acc0 = dst[(size_t)n * 48 + lane];
  float4 acc1 = {0.f, 0.f, 0.f, 0.f};
#pragma unroll 1
  for (int pass = 0; pass < 2; ++pass) {
    const int* rp  = pass ? rp_b : rp_f;
    const int* col = pass ? col_b : col_f;
    const float* wn = pass ? wn_b : wn_f;
    const float4* src = pass ? s2 : s1;
    const int e0 = rp[n], e1 = rp[n + 1];
    int e = e0;
    for (; e + 1 < e1; e += 2) {
      const int c0 = col[e], c1 = col[e + 1];
      const float w0 = wn[e], w1 = wn[e + 1];
      float4 v0 = src[(size_t)c0 * 48 + lane];
      float4 v1 = src[(size_t)c1 * 48 + lane];
      acc0.x = fmaf(w0, v0.x, acc0.x); acc1.x = fmaf(w1, v1.x, acc1.x);
      acc0.y = fmaf(w0, v0.y, acc0.y); acc1.y = fmaf(w1, v1.y, acc1.y);
      acc0.z = fmaf(w0, v0.z, acc0.z); acc1.z = fmaf(w1, v1.z, acc1.z);
      acc0.w = fmaf(w0, v0.w, acc0.w); acc1.w = fmaf(w1, v1.w, acc1.w);
    }
    if (e < e1) {
      const int c0 = col[e];
      const float w0 = wn[e];
      float4 v0 = src[(size_t)c0 * 48 + lane];
      acc0.x = fmaf(w0, v0.x, acc0.x);
      acc0.y = fmaf(w0, v0.y, acc0.y);
      acc0.z = fmaf(w0, v0.z, acc0.z);
      acc0.w = fmaf(w0, v0.w, acc0.w);
    }
  }
  acc0.x += acc1.x; acc0.y += acc1.y; acc0.z += acc1.z; acc0.w += acc1.w;
  dst[(size_t)n * 48 + lane] = acc0;
}

// ---------------------------------------------------------------- G0[n][b][24] -> out[b][t][n][f]
__global__ __launch_bounds__(256) void reorder_kernel(const float* __restrict__ G0,
                                                      float* __restrict__ out) {
  __shared__ float tile[32 * 193];
  const int n0 = blockIdx.x * 32;
  const int tid = threadIdx.x;
  for (int idx = tid; idx < 6144; idx += 256) {
    int i = idx / 192, r = idx - i * 192;
    tile[i * 193 + r] = G0[(size_t)n0 * 192 + idx];
  }
  __syncthreads();
  for (int idx = tid; idx < 6144; idx += 256) {
    int b = idx / 768;
    int rem = idx - b * 768;
    int t = rem >> 6;
    int rem2 = rem & 63;
    int i = rem2 >> 1, f = rem2 & 1;
    out[(((size_t)b * NT + t) * NN + n0 + i) * 2 + f] = tile[i * 193 + b * 24 + t * 2 + f];
  }
}

// ----------------------------------------------------------------
extern "C" void kernel_launch(void* const* d_in, const int* in_sizes, int n_in,
                              void* d_out, int out_size, void* d_ws, size_t ws_size,
                              hipStream_t stream) {
  const float* x        = (const float*)d_in[0];
  const int*   ei       = (const int*)d_in[1];
  const float* ew       = (const float*)d_in[2];
  const float* enc_w    = (const float*)d_in[3];
  const float* enc_b    = (const float*)d_in[4];
  const float* node_emb = (const float*)d_in[5];
  const float* w_ih     = (const float*)d_in[6];
  const float* w_hh     = (const float*)d_in[7];
  const float* b_ih     = (const float*)d_in[8];
  const float* b_hh     = (const float*)d_in[9];
  const float* filt_w   = (const float*)d_in[10];
  const float* filt_b   = (const float*)d_in[11];
  const float* dec_w    = (const float*)d_in[12];
  const float* dec_b    = (const float*)d_in[13];
  float* out = (float*)d_out;

  char* p = (char*)d_ws;
  auto alloc = [&](size_t bytes) {
    char* r = p;
    p += (bytes + 255) & ~(size_t)255;
    return r;
  };
  const size_t BN24 = (size_t)NB * NN * 24;
  float* G0   = (float*)alloc(BN24 * 4);
  float* G1f  = (float*)alloc(BN24 * 4);
  float* G2f  = (float*)alloc(BN24 * 4);
  float* G1b  = (float*)alloc(BN24 * 4);
  float* G2b  = (float*)alloc(BN24 * 4);
  float* nbq  = (float*)alloc((size_t)NN * 192 * 4);
  int* rp_f   = (int*)alloc((NN + 1) * 4);
  int* rp_b   = (int*)alloc((NN + 1) * 4);
  char* zreg  = alloc(4 * NN * 4);        // wsum_f, wsum_b, cnt_f, cnt_b (zeroed)
  float* wsum_f = (float*)zreg;
  float* wsum_b = wsum_f + NN;
  int*   cnt_f  = (int*)(wsum_b + NN);
  int*   cnt_b  = cnt_f + NN;
  int* cur_f  = (int*)alloc(NN * 4);
  int* cur_b  = (int*)alloc(NN * 4);
  int* col_f  = (int*)alloc((size_t)NE * 4);
  float* wn_f = (float*)alloc((size_t)NE * 4);
  int* col_b  = (int*)alloc((size_t)NE * 4);
  float* wn_b = (float*)alloc((size_t)NE * 4);
  float* Wcat = (float*)alloc(64 * 128 * 4);
  float* cbv  = (float*)alloc(32 * 4);
  float* W2   = (float*)alloc(384 * 4);

  hipMemsetAsync(zreg, 0, 4 * NN * 4, stream);
  deg_kernel<<<(NE + 255) / 256, 256, 0, stream>>>(ei, ew, wsum_f, wsum_b, cnt_f, cnt_b);
  scan_kernel<<<1, 1024, 0, stream>>>(cnt_f, cnt_b, rp_f, rp_b, cur_f, cur_b);
  fill_kernel<<<(NE + 255) / 256, 256, 0, stream>>>(ei, ew, wsum_f, wsum_b, cur_f, cur_b,
                                                    col_f, wn_f, col_b, wn_b);
  nb_kernel<<<NBLK_NB + 17, 512, 0, stream>>>(node_emb, enc_b, w_ih, b_ih, enc_w, b_hh,
                                              filt_w, filt_b, dec_w, dec_b,
                                              nbq, W2, Wcat, cbv);
  gru_kernel<<<(NB * NN) / 64, 256, 0, stream>>>(x, nbq, W2, b_hh, w_hh, Wcat, cbv,
                                                 G0, G1f, G2f, G1b, G2b);
  hop1_kernel<<<2 * NN / 4, 256, 0, stream>>>(G1f, G2f, G1b, G2b,
                                              rp_f, col_f, wn_f, rp_b, col_b, wn_b);
  hop2_kernel<<<NN / 4, 256, 0, stream>>>(G0, G1f, G1b,
                                          rp_f, col_f, wn_f, rp_b, col_b, wn_b);
  reorder_kernel<<<NN / 32, 256, 0, stream>>>(G0, out);
}